// Round 1
// baseline (24220.821 us; speedup 1.0000x reference)
//
#include <hip/hip_runtime.h>
#include <hip/hip_bf16.h>
#include <cstdint>
#include <cstddef>

// Problem constants (fixed by the reference)
#define BB   256   // batch
#define SS   512   // encoder seq len
#define RDIM 128   // embed dim
#define HH   512   // hidden
#define TT   96    // decoder steps

typedef unsigned int u32;

__device__ __forceinline__ float sigm(float x){ return 1.0f/(1.0f+__expf(-x)); }
__device__ __forceinline__ float tanh_f(float x){ return 1.0f - 2.0f/(__expf(2.0f*x)+1.0f); }
__device__ __forceinline__ float blo(u32 x){ return __uint_as_float(x << 16); }
__device__ __forceinline__ float bhi(u32 x){ return __uint_as_float(x & 0xffff0000u); }

// ---------------------------------------------------------------------------
// Prep kernels (run once per call; weights reorganized into ws)
// ---------------------------------------------------------------------------

// u[n] = sum_r Wih[n,r]*embW[r] ; v[n] = sum_r Wih[n,r]*embB[r] + bih[n] + bhh[n]
// bd[n] = dec_bih[n] + dec_bhh[n]
__global__ void prep_uv(const float* __restrict__ Wih, const float* __restrict__ embW,
                        const float* __restrict__ embB, const float* __restrict__ bih,
                        const float* __restrict__ bhh, const float* __restrict__ dbih,
                        const float* __restrict__ dbhh,
                        float* __restrict__ u, float* __restrict__ v, float* __restrict__ bd){
  int n = blockIdx.x*256 + threadIdx.x;   // 0..2047
  const float* row = Wih + (size_t)n*RDIM;
  float su = 0.f, sv = 0.f;
  for(int r=0;r<RDIM;r++){ float w = row[r]; su += w*embW[r]; sv += w*embB[r]; }
  u[n] = su;
  v[n] = sv + bih[n] + bhh[n];
  bd[n] = dbih[n] + dbhh[n];
}

// Reorder Whh [2048,512] -> Whh_r[32 colblk][64 rows][512] where row = g*16+jc maps
// to source row g*512 + blk*16 + jc  (so each GEMM block reads one contiguous chunk)
__global__ void prep_whh(const float* __restrict__ Whh, float* __restrict__ Whh_r){
  int blk = blockIdx.x;          // 0..31
  int r   = blockIdx.y;          // 0..63
  int g = r>>4, jc = r&15;
  int srow = g*HH + blk*16 + jc;
  const float4* src = (const float4*)(Whh + (size_t)srow*HH);
  float4* dst = (float4*)(Whh_r + ((size_t)blk*64 + r)*HH);
  dst[threadIdx.x] = src[threadIdx.x];   // 128 threads * 16B = 512 floats
}

// Wd_r[32][64][1024]: k<512 -> dec_Wih[n,k]+dec_Whh[n,k]; k>=512 -> dec_Wih[n,k]
__global__ void prep_wd(const float* __restrict__ dWih, const float* __restrict__ dWhh,
                        float* __restrict__ Wd_r){
  int blk = blockIdx.x, r = blockIdx.y;
  int g = r>>4, jc = r&15;
  int n = g*HH + blk*16 + jc;
  float* dst = Wd_r + ((size_t)blk*64 + r)*1024;
  for(int k=threadIdx.x; k<1024; k+=256){
    float wv = dWih[(size_t)n*1024 + k];
    if(k < HH) wv += dWhh[(size_t)n*HH + k];
    dst[k] = wv;
  }
}

// Wqk_t[n][a] = sum_h' Wq[h',a] * Wk[h',n]   (stored n-major for the qproj GEMM)
__global__ void prep_wqk(const float* __restrict__ Wq, const float* __restrict__ Wk,
                         float* __restrict__ Wqk_t){
  __shared__ float wkc[HH];
  int n = blockIdx.x;  // 0..511
  for(int i=threadIdx.x;i<HH;i+=256) wkc[i] = Wk[(size_t)i*HH + n];
  __syncthreads();
  for(int a=threadIdx.x;a<HH;a+=256){
    float s = 0.f;
    for(int hp=0;hp<HH;hp++) s += Wq[(size_t)hp*HH + a]*wkc[hp];
    Wqk_t[(size_t)n*HH + a] = s;
  }
}

// bqk[n] = sum_h' bq[h'] * Wk[h',n]
__global__ void prep_bqk(const float* __restrict__ bq, const float* __restrict__ Wk,
                         float* __restrict__ bqk){
  int n = blockIdx.x*256 + threadIdx.x;  // 0..511
  float s = 0.f;
  for(int hp=0;hp<HH;hp++) s += bq[hp]*Wk[(size_t)hp*HH + n];
  bqk[n] = s;
}

// ---------------------------------------------------------------------------
// Encoder step: gates[b, 4H] = e[b,t]*u + v + h@Whh.T ; LSTM update; store h
// grid (8, 32): block = 32 batch rows x 16 h-cols (= 64 gate cols). 256 threads.
// Register tile 2x4 per thread, float4 LDS reads along K.
// ---------------------------------------------------------------------------
__launch_bounds__(256)
__global__ void enc_step(const float* __restrict__ hin, float* __restrict__ hout,
                         float* __restrict__ cbuf, const float* __restrict__ Whh_r,
                         const float* __restrict__ u, const float* __restrict__ v,
                         const float* __restrict__ einp,
                         __hip_bfloat16* __restrict__ hx, int t){
  __shared__ float hs[32][36];
  __shared__ float wsm[64][36];
  __shared__ float gt[64][33];
  const int tid = threadIdx.x;
  const int b0 = blockIdx.x*32;
  const int jb = blockIdx.y;
  const int j0 = jb*16;
  const float* wr = Whh_r + (size_t)jb*64*HH;

  const int rp = tid & 15;       // rows rp, rp+16
  const int cp = tid >> 4;       // cols cp*4 .. cp*4+3  (of 64 gate cols)

  float acc[2][4];
  {
    float e0 = einp[(size_t)(b0+rp)*SS + t];
    float e1 = einp[(size_t)(b0+rp+16)*SS + t];
    #pragma unroll
    for(int j=0;j<4;j++){
      int c = cp*4 + j;
      int n = (c>>4)*HH + j0 + (c&15);
      float uu = u[n], vv = v[n];
      acc[0][j] = e0*uu + vv;
      acc[1][j] = e1*uu + vv;
    }
  }

  const int hrow = tid>>3, hkq = (tid&7)*4;   // h staging: 32x32
  const int wrow = tid>>2, wkq = (tid&3)*8;   // W staging: 64x32

  for(int k0=0;k0<HH;k0+=32){
    float4 hv4 = *(const float4*)(hin + (size_t)(b0+hrow)*HH + k0 + hkq);
    float4 wv0 = *(const float4*)(wr + (size_t)wrow*HH + k0 + wkq);
    float4 wv1 = *(const float4*)(wr + (size_t)wrow*HH + k0 + wkq + 4);
    *(float4*)&hs[hrow][hkq]    = hv4;
    *(float4*)&wsm[wrow][wkq]   = wv0;
    *(float4*)&wsm[wrow][wkq+4] = wv1;
    __syncthreads();
    #pragma unroll
    for(int kq=0;kq<8;kq++){
      float4 ha = *(const float4*)&hs[rp][kq*4];
      float4 hb = *(const float4*)&hs[rp+16][kq*4];
      #pragma unroll
      for(int j=0;j<4;j++){
        float4 wv = *(const float4*)&wsm[cp*4+j][kq*4];
        acc[0][j] = fmaf(ha.x, wv.x, acc[0][j]);
        acc[0][j] = fmaf(ha.y, wv.y, acc[0][j]);
        acc[0][j] = fmaf(ha.z, wv.z, acc[0][j]);
        acc[0][j] = fmaf(ha.w, wv.w, acc[0][j]);
        acc[1][j] = fmaf(hb.x, wv.x, acc[1][j]);
        acc[1][j] = fmaf(hb.y, wv.y, acc[1][j]);
        acc[1][j] = fmaf(hb.z, wv.z, acc[1][j]);
        acc[1][j] = fmaf(hb.w, wv.w, acc[1][j]);
      }
    }
    __syncthreads();
  }

  #pragma unroll
  for(int j=0;j<4;j++){
    gt[cp*4+j][rp]    = acc[0][j];
    gt[cp*4+j][rp+16] = acc[1][j];
  }
  __syncthreads();

  // epilogue: 512 h-elements, 2 per thread; gate col c = g*16 + jc
  #pragma unroll
  for(int q=0;q<2;q++){
    int idx = tid + q*256;
    int jc = idx & 15, rr = idx >> 4;
    float gi = gt[jc][rr];
    float gf = gt[16+jc][rr];
    float gg = gt[32+jc][rr];
    float go = gt[48+jc][rr];
    int b = b0 + rr, j = j0 + jc;
    size_t ci = (size_t)b*HH + j;
    float cv = sigm(gf)*cbuf[ci] + sigm(gi)*tanh_f(gg);
    cbuf[ci] = cv;
    float hv = sigm(go)*tanh_f(cv);
    hout[ci] = hv;
    hx[((size_t)b*SS + t)*HH + j] = __float2bfloat16(hv);
  }
}

// ---------------------------------------------------------------------------
// qproj: qt = h @ Wqk_t.T(+bqk) : [256,512]@[512,512]. grid (8,16), 256 thr.
// ---------------------------------------------------------------------------
__launch_bounds__(256)
__global__ void qproj(const float* __restrict__ hin, const float* __restrict__ Wqk_t,
                      const float* __restrict__ bqk, float* __restrict__ qt){
  __shared__ float hs[32][36];
  __shared__ float wsm[32][36];
  const int tid = threadIdx.x;
  const int b0 = blockIdx.x*32, n0 = blockIdx.y*32;
  const int rp = tid & 15, cp = tid >> 4;   // rows rp,rp+16; cols cp*2, cp*2+1
  float acc[2][2];
  acc[0][0] = acc[1][0] = bqk[n0 + cp*2];
  acc[0][1] = acc[1][1] = bqk[n0 + cp*2 + 1];
  const int srow = tid>>3, skq = (tid&7)*4;
  for(int k0=0;k0<HH;k0+=32){
    *(float4*)&hs[srow][skq]  = *(const float4*)(hin  + (size_t)(b0+srow)*HH + k0 + skq);
    *(float4*)&wsm[srow][skq] = *(const float4*)(Wqk_t + (size_t)(n0+srow)*HH + k0 + skq);
    __syncthreads();
    #pragma unroll
    for(int kq=0;kq<8;kq++){
      float4 ha = *(const float4*)&hs[rp][kq*4];
      float4 hb = *(const float4*)&hs[rp+16][kq*4];
      #pragma unroll
      for(int j=0;j<2;j++){
        float4 wv = *(const float4*)&wsm[cp*2+j][kq*4];
        acc[0][j] = fmaf(ha.x,wv.x,acc[0][j]); acc[0][j] = fmaf(ha.y,wv.y,acc[0][j]);
        acc[0][j] = fmaf(ha.z,wv.z,acc[0][j]); acc[0][j] = fmaf(ha.w,wv.w,acc[0][j]);
        acc[1][j] = fmaf(hb.x,wv.x,acc[1][j]); acc[1][j] = fmaf(hb.y,wv.y,acc[1][j]);
        acc[1][j] = fmaf(hb.z,wv.z,acc[1][j]); acc[1][j] = fmaf(hb.w,wv.w,acc[1][j]);
      }
    }
    __syncthreads();
  }
  #pragma unroll
  for(int j=0;j<2;j++){
    qt[(size_t)(b0+rp)*HH    + n0 + cp*2 + j] = acc[0][j];
    qt[(size_t)(b0+rp+16)*HH + n0 + cp*2 + j] = acc[1][j];
  }
}

// ---------------------------------------------------------------------------
// Attention (flash-style, one block per batch row, online softmax over S=512)
// scores[s] = qt[b] . in_hxs[b,s]  (bf16 operand, f32 accum)
// ctx[b]    = softmax(scores) @ in_hxs[b]
// ---------------------------------------------------------------------------
__launch_bounds__(256)
__global__ void attn(const float* __restrict__ qt, const __hip_bfloat16* __restrict__ hx,
                     float* __restrict__ ctx){
  __shared__ unsigned short xs[32][520];   // 32 seq rows x 512 bf16 (+pad, 16B-aligned rows)
  __shared__ float sc[32];
  const int b = blockIdx.x, tid = threadIdx.x;
  const int seg = tid & 7;    // 64-wide h-chunk for score partial
  const int sp  = tid >> 3;   // s within tile

  float qreg[64];
  {
    const float4* qv = (const float4*)(qt + (size_t)b*HH + seg*64);
    #pragma unroll
    for(int i=0;i<16;i++){
      float4 v4 = qv[i];
      qreg[i*4+0]=v4.x; qreg[i*4+1]=v4.y; qreg[i*4+2]=v4.z; qreg[i*4+3]=v4.w;
    }
  }

  float m = -1e30f, l = 0.f, a0 = 0.f, a1 = 0.f;
  const uint4* src = (const uint4*)(hx + (size_t)b*SS*HH);

  for(int tile=0; tile<16; ++tile){
    __syncthreads();                       // protect xs vs previous tile's readers
    const uint4* tsrc = src + (size_t)tile*2048;
    #pragma unroll
    for(int kk=0;kk<8;kk++){
      uint4 vv = tsrc[kk*256 + tid];       // fully coalesced
      int e  = (kk*256 + tid)*8;
      int ss = e >> 9, hh = e & 511;
      *(uint4*)&xs[ss][hh] = vv;
    }
    __syncthreads();

    // scores: 8 threads per s, 64 h each, shuffle-reduce within groups of 8
    float p = 0.f;
    const uint4* xrow = (const uint4*)&xs[sp][seg*64];
    #pragma unroll
    for(int i=0;i<8;i++){
      uint4 vv = xrow[i];
      p = fmaf(qreg[i*8+0], blo(vv.x), p);
      p = fmaf(qreg[i*8+1], bhi(vv.x), p);
      p = fmaf(qreg[i*8+2], blo(vv.y), p);
      p = fmaf(qreg[i*8+3], bhi(vv.y), p);
      p = fmaf(qreg[i*8+4], blo(vv.z), p);
      p = fmaf(qreg[i*8+5], bhi(vv.z), p);
      p = fmaf(qreg[i*8+6], blo(vv.w), p);
      p = fmaf(qreg[i*8+7], bhi(vv.w), p);
    }
    p += __shfl_xor(p, 1);
    p += __shfl_xor(p, 2);
    p += __shfl_xor(p, 4);
    if(seg == 0) sc[sp] = p;
    __syncthreads();

    // online softmax update (replicated per thread; deterministic)
    float tmax = -1e30f;
    #pragma unroll
    for(int s2=0;s2<32;s2++) tmax = fmaxf(tmax, sc[s2]);
    float mnew  = fmaxf(m, tmax);
    float alpha = __expf(m - mnew);
    a0 *= alpha; a1 *= alpha; l *= alpha;
    #pragma unroll 4
    for(int s2=0;s2<32;s2++){
      float pv = __expf(sc[s2] - mnew);
      l += pv;
      u32 xv = *(const u32*)&xs[s2][2*tid];  // 2 bf16 = cols 2*tid, 2*tid+1
      a0 = fmaf(pv, blo(xv), a0);
      a1 = fmaf(pv, bhi(xv), a1);
    }
    m = mnew;
  }
  float inv = 1.0f/l;
  ctx[(size_t)b*HH + 2*tid]     = a0*inv;
  ctx[(size_t)b*HH + 2*tid + 1] = a1*inv;
}

// ---------------------------------------------------------------------------
// Decoder step: gates = [h|ctx] @ Wd.T + bd ; LSTM update; store h into hdec
// grid (8,32), K = 1024
// ---------------------------------------------------------------------------
__launch_bounds__(256)
__global__ void dec_step(const float* __restrict__ hin, float* __restrict__ hout,
                         float* __restrict__ cbuf, const float* __restrict__ ctxv,
                         const float* __restrict__ Wd_r, const float* __restrict__ bd,
                         float* __restrict__ hdec, int t){
  __shared__ float hs[32][36];
  __shared__ float wsm[64][36];
  __shared__ float gt[64][33];
  const int tid = threadIdx.x;
  const int b0 = blockIdx.x*32;
  const int jb = blockIdx.y;
  const int j0 = jb*16;
  const float* wr = Wd_r + (size_t)jb*64*1024;
  const int rp = tid & 15, cp = tid >> 4;

  float acc[2][4];
  #pragma unroll
  for(int j=0;j<4;j++){
    int c = cp*4 + j;
    int n = (c>>4)*HH + j0 + (c&15);
    acc[0][j] = acc[1][j] = bd[n];
  }

  const int hrow = tid>>3, hkq = (tid&7)*4;
  const int wrow = tid>>2, wkq = (tid&3)*8;

  for(int k0=0;k0<1024;k0+=32){
    const float* asrc = (k0 < HH) ? (hin  + (size_t)(b0+hrow)*HH + k0 + hkq)
                                  : (ctxv + (size_t)(b0+hrow)*HH + (k0-HH) + hkq);
    float4 hv4 = *(const float4*)asrc;
    float4 wv0 = *(const float4*)(wr + (size_t)wrow*1024 + k0 + wkq);
    float4 wv1 = *(const float4*)(wr + (size_t)wrow*1024 + k0 + wkq + 4);
    *(float4*)&hs[hrow][hkq]    = hv4;
    *(float4*)&wsm[wrow][wkq]   = wv0;
    *(float4*)&wsm[wrow][wkq+4] = wv1;
    __syncthreads();
    #pragma unroll
    for(int kq=0;kq<8;kq++){
      float4 ha = *(const float4*)&hs[rp][kq*4];
      float4 hb = *(const float4*)&hs[rp+16][kq*4];
      #pragma unroll
      for(int j=0;j<4;j++){
        float4 wv = *(const float4*)&wsm[cp*4+j][kq*4];
        acc[0][j] = fmaf(ha.x, wv.x, acc[0][j]);
        acc[0][j] = fmaf(ha.y, wv.y, acc[0][j]);
        acc[0][j] = fmaf(ha.z, wv.z, acc[0][j]);
        acc[0][j] = fmaf(ha.w, wv.w, acc[0][j]);
        acc[1][j] = fmaf(hb.x, wv.x, acc[1][j]);
        acc[1][j] = fmaf(hb.y, wv.y, acc[1][j]);
        acc[1][j] = fmaf(hb.z, wv.z, acc[1][j]);
        acc[1][j] = fmaf(hb.w, wv.w, acc[1][j]);
      }
    }
    __syncthreads();
  }

  #pragma unroll
  for(int j=0;j<4;j++){
    gt[cp*4+j][rp]    = acc[0][j];
    gt[cp*4+j][rp+16] = acc[1][j];
  }
  __syncthreads();

  #pragma unroll
  for(int q=0;q<2;q++){
    int idx = tid + q*256;
    int jc = idx & 15, rr = idx >> 4;
    float gi = gt[jc][rr];
    float gf = gt[16+jc][rr];
    float gg = gt[32+jc][rr];
    float go = gt[48+jc][rr];
    int b = b0 + rr, j = j0 + jc;
    size_t ci = (size_t)b*HH + j;
    float cv = sigm(gf)*cbuf[ci] + sigm(gi)*tanh_f(gg);
    cbuf[ci] = cv;
    float hv = sigm(go)*tanh_f(cv);
    hout[ci] = hv;
    hdec[((size_t)t*BB + b)*HH + j] = hv;
  }
}

// out[b,t] = hdec[t,b,:] . out_W + out_b
__launch_bounds__(256)
__global__ void final_out(const float* __restrict__ hdec, const float* __restrict__ outW,
                          const float* __restrict__ outb, float* __restrict__ out){
  __shared__ float w[HH];
  int t = blockIdx.x;       // 96
  for(int i=threadIdx.x;i<HH;i+=256) w[i] = outW[i];
  __syncthreads();
  int b = threadIdx.x;      // 256
  const float4* hp = (const float4*)(hdec + ((size_t)t*BB + b)*HH);
  float s = 0.f;
  #pragma unroll 4
  for(int j=0;j<HH/4;j++){
    float4 hv = hp[j];
    s = fmaf(hv.x, w[j*4+0], s);
    s = fmaf(hv.y, w[j*4+1], s);
    s = fmaf(hv.z, w[j*4+2], s);
    s = fmaf(hv.w, w[j*4+3], s);
  }
  out[(size_t)b*TT + t] = s + outb[0];
}

// ---------------------------------------------------------------------------
extern "C" void kernel_launch(void* const* d_in, const int* in_sizes, int n_in,
                              void* d_out, int out_size, void* d_ws, size_t ws_size,
                              hipStream_t stream){
  const float* enc_in = (const float*)d_in[0];
  // d_in[1]: out_seq_len (int scalar) — fixed at 96
  const float* embW = (const float*)d_in[2];
  const float* embB = (const float*)d_in[3];
  const float* eWih = (const float*)d_in[4];
  const float* eWhh = (const float*)d_in[5];
  const float* ebih = (const float*)d_in[6];
  const float* ebhh = (const float*)d_in[7];
  const float* dWih = (const float*)d_in[8];
  const float* dWhh = (const float*)d_in[9];
  const float* dbih = (const float*)d_in[10];
  const float* dbhh = (const float*)d_in[11];
  const float* Wq   = (const float*)d_in[12];
  const float* bq   = (const float*)d_in[13];
  const float* Wk   = (const float*)d_in[14];
  // d_in[15]: bk — softmax-invariant, provably unused
  const float* outW = (const float*)d_in[16];
  const float* outb = (const float*)d_in[17];

  // workspace layout (float offsets); total ~201 MB
  float* ws = (float*)d_ws;
  float* Whh_r = ws;                        // 1,048,576
  float* Wd_r  = ws + 1048576;              // 2,097,152
  float* Wqk_t = ws + 3145728;              //   262,144
  float* u     = ws + 3407872;              //     2,048
  float* v     = ws + 3409920;              //     2,048
  float* bd    = ws + 3411968;              //     2,048
  float* bqk   = ws + 3414016;              //       512
  float* hb0   = ws + 3414528;              //   131,072
  float* hb1   = ws + 3545600;              //   131,072
  float* cb    = ws + 3676672;              //   131,072
  float* ctx   = ws + 3807744;              //   131,072
  float* qt    = ws + 3938816;              //   131,072
  float* hdec  = ws + 4069888;              // 12,582,912
  __hip_bfloat16* hx = (__hip_bfloat16*)(ws + 16652800);  // 67,108,864 bf16

  hipMemsetAsync(hb0, 0, (size_t)BB*HH*sizeof(float), stream);
  hipMemsetAsync(cb,  0, (size_t)BB*HH*sizeof(float), stream);

  prep_uv <<<8, 256, 0, stream>>>(eWih, embW, embB, ebih, ebhh, dbih, dbhh, u, v, bd);
  prep_whh<<<dim3(32,64), 128, 0, stream>>>(eWhh, Whh_r);
  prep_wd <<<dim3(32,64), 256, 0, stream>>>(dWih, dWhh, Wd_r);
  prep_wqk<<<512, 256, 0, stream>>>(Wq, Wk, Wqk_t);
  prep_bqk<<<2, 256, 0, stream>>>(bq, Wk, bqk);

  float* hbuf[2] = {hb0, hb1};
  for(int t=0;t<SS;t++){
    enc_step<<<dim3(8,32), 256, 0, stream>>>(hbuf[t&1], hbuf[(t+1)&1], cb,
                                             Whh_r, u, v, enc_in, hx, t);
  }
  for(int t=0;t<TT;t++){
    qproj   <<<dim3(8,16), 256, 0, stream>>>(hbuf[t&1], Wqk_t, bqk, qt);
    attn    <<<256, 256, 0, stream>>>(qt, hx, ctx);
    dec_step<<<dim3(8,32), 256, 0, stream>>>(hbuf[t&1], hbuf[(t+1)&1], cb, ctx,
                                             Wd_r, bd, hdec, t);
  }
  final_out<<<TT, 256, 0, stream>>>(hdec, outW, outb, (float*)d_out);
}

// Round 2
// 7399.454 us; speedup vs baseline: 3.2733x; 3.2733x over previous
//
#include <hip/hip_runtime.h>
#include <hip/hip_bf16.h>
#include <cstdint>
#include <cstddef>

#define BB   256   // batch
#define SS   512   // encoder seq len
#define RDIM 128   // embed dim
#define HH   512   // hidden
#define TT   96    // decoder steps

typedef unsigned int u32;
typedef _Float16 f16;
typedef __attribute__((ext_vector_type(8))) _Float16 f16x8;
typedef __attribute__((ext_vector_type(4))) float f32x4;

__device__ __forceinline__ float sigm(float x){ return 1.0f/(1.0f+__expf(-x)); }
__device__ __forceinline__ float tanh_f(float x){ return 1.0f - 2.0f/(__expf(2.0f*x)+1.0f); }
__device__ __forceinline__ float2 cvt2(u32 x){
  union { u32 u; f16 h[2]; } t; t.u = x;
  return make_float2((float)t.h[0], (float)t.h[1]);
}

// ---------------------------------------------------------------------------
// Prep kernels
// ---------------------------------------------------------------------------

// u[n]=Wih[n,:]@embW ; v[n]=Wih[n,:]@embB + bih + bhh ; bd[n]=dec_bih+dec_bhh
__global__ void prep_uv(const float* __restrict__ Wih, const float* __restrict__ embW,
                        const float* __restrict__ embB, const float* __restrict__ bih,
                        const float* __restrict__ bhh, const float* __restrict__ dbih,
                        const float* __restrict__ dbhh,
                        float* __restrict__ u, float* __restrict__ v, float* __restrict__ bd){
  int n = blockIdx.x*256 + threadIdx.x;   // 0..2047
  const float* row = Wih + (size_t)n*RDIM;
  float su = 0.f, sv = 0.f;
  for(int r=0;r<RDIM;r++){ float w = row[r]; su += w*embW[r]; sv += w*embB[r]; }
  u[n] = su;
  v[n] = sv + bih[n] + bhh[n];
  bd[n] = dbih[n] + dbhh[n];
}

// Wqk_t[n][a] = sum_h' Wq[h',a] * Wk[h',n]
__global__ void prep_wqk(const float* __restrict__ Wq, const float* __restrict__ Wk,
                         float* __restrict__ Wqk_t){
  __shared__ float wkc[HH];
  int n = blockIdx.x;
  for(int i=threadIdx.x;i<HH;i+=256) wkc[i] = Wk[(size_t)i*HH + n];
  __syncthreads();
  for(int a=threadIdx.x;a<HH;a+=256){
    float s = 0.f;
    for(int hp=0;hp<HH;hp++) s += Wq[(size_t)hp*HH + a]*wkc[hp];
    Wqk_t[(size_t)n*HH + a] = s;
  }
}

// bqk[n] = sum_h' bq[h'] * Wk[h',n]
__global__ void prep_bqk(const float* __restrict__ bq, const float* __restrict__ Wk,
                         float* __restrict__ bqk){
  int n = blockIdx.x*256 + threadIdx.x;
  float s = 0.f;
  for(int hp=0;hp<HH;hp++) s += bq[hp]*Wk[(size_t)hp*HH + n];
  bqk[n] = s;
}

// Encoder weights -> fragment-major f16: Wfm[((nt*17+kk)*64+L)*8+j]
// nt=jb*4+ct (jb 0..31, ct=gate 0..3); n = ct*512 + jb*16 + (L&15); k = kk*32 + (L>>4)*8 + j
// kk==16 (ext chunk): k=512 -> u[n], k=513 -> v[n], else 0
__global__ void prep_wenc(const float* __restrict__ Whh, const float* __restrict__ u,
                          const float* __restrict__ v, f16* __restrict__ Wfm){
  int nt = blockIdx.x, kk = blockIdx.y, L = threadIdx.x;
  int jb = nt>>2, ct = nt&3;
  int n = ct*HH + jb*16 + (L&15);
  int q = L>>4;
  union { f16 h[8]; uint4 u4; } z;
  if(kk < 16){
    const float* src = Whh + (size_t)n*HH + kk*32 + q*8;
    #pragma unroll
    for(int j=0;j<8;j++) z.h[j] = (f16)src[j];
  } else {
    #pragma unroll
    for(int j=0;j<8;j++) z.h[j] = (f16)0.0f;
    if(q==0){ z.h[0] = (f16)u[n]; z.h[1] = (f16)v[n]; }
  }
  *(uint4*)(Wfm + (((size_t)nt*17 + kk)*64 + L)*8) = z.u4;
}

// Decoder weights: Wd[n][k] = dWih[n][k] + (k<512 ? dWhh[n][k] : 0); ext k=1024 -> bd[n]
// nt = jb*8+ct (jb 0..15, ct 0..7); n = (ct>>1)*512 + jb*32 + (ct&1)*16 + (L&15)
__global__ void prep_wdec(const float* __restrict__ dWih, const float* __restrict__ dWhh,
                          const float* __restrict__ bd, f16* __restrict__ Wfm){
  int nt = blockIdx.x, kk = blockIdx.y, L = threadIdx.x;
  int jb = nt>>3, ct = nt&7;
  int n = (ct>>1)*HH + jb*32 + (ct&1)*16 + (L&15);
  int q = L>>4;
  union { f16 h[8]; uint4 u4; } z;
  if(kk < 32){
    int k0 = kk*32 + q*8;
    #pragma unroll
    for(int j=0;j<8;j++){
      float wv = dWih[(size_t)n*1024 + k0 + j];
      if(k0 + j < HH) wv += dWhh[(size_t)n*HH + k0 + j];
      z.h[j] = (f16)wv;
    }
  } else {
    #pragma unroll
    for(int j=0;j<8;j++) z.h[j] = (f16)0.0f;
    if(q==0) z.h[0] = (f16)bd[n];
  }
  *(uint4*)(Wfm + (((size_t)nt*33 + kk)*64 + L)*8) = z.u4;
}

// Wqk fragment-major: nt 0..31, n = nt*16 + (L&15); ext k=512 -> bqk[n]
__global__ void prep_wqfm(const float* __restrict__ Wqk_t, const float* __restrict__ bqk,
                          f16* __restrict__ Wfm){
  int nt = blockIdx.x, kk = blockIdx.y, L = threadIdx.x;
  int n = nt*16 + (L&15);
  int q = L>>4;
  union { f16 h[8]; uint4 u4; } z;
  if(kk < 16){
    const float* src = Wqk_t + (size_t)n*HH + kk*32 + q*8;
    #pragma unroll
    for(int j=0;j<8;j++) z.h[j] = (f16)src[j];
  } else {
    #pragma unroll
    for(int j=0;j<8;j++) z.h[j] = (f16)0.0f;
    if(q==0) z.h[0] = (f16)bqk[n];
  }
  *(uint4*)(Wfm + (((size_t)nt*17 + kk)*64 + L)*8) = z.u4;
}

// ---------------------------------------------------------------------------
// Encoder step (MFMA): block = 32 batch x 64 gate-cols, grid (8,32)
// h_ext = [h(512) | e | 1 | 0...] (544), W_ext = [Whh | u | v | 0...]
// ---------------------------------------------------------------------------
#define STR 552   // LDS row stride in f16 (544 data + 8 pad; 1104B: A-reads 2-way only)

__launch_bounds__(256)
__global__ void enc_step(const f16* __restrict__ hin, f16* __restrict__ hout,
                         float* __restrict__ cbuf, const f16* __restrict__ Wfm,
                         const float* __restrict__ einp, f16* __restrict__ hx, int t){
  __shared__ f16 hsm[32*STR];
  __shared__ float gt[64][33];
  const int tid = threadIdx.x;
  const int b0 = blockIdx.x*32, jb = blockIdx.y;

  {
    int row = tid>>3, c0 = tid&7;
    const uint4* src = (const uint4*)(hin + (size_t)(b0+row)*HH);
    uint4* drow = (uint4*)(hsm + row*STR);
    #pragma unroll
    for(int i=0;i<8;i++) drow[c0 + 8*i] = src[c0 + 8*i];
  }
  if(tid < 128){
    int row = tid>>2, pc = tid&3;
    union { f16 h[8]; uint4 u4; } z;
    #pragma unroll
    for(int j=0;j<8;j++) z.h[j] = (f16)0.0f;
    if(pc==0){ z.h[0] = (f16)einp[(size_t)(b0+row)*SS + t]; z.h[1] = (f16)1.0f; }
    *((uint4*)(hsm + row*STR) + 64 + pc) = z.u4;
  }
  __syncthreads();

  const int lane = tid & 63, w = tid>>6;
  const int rt = w & 1, ctb = (w>>1)*2;
  const int m = lane & 15, q = lane>>4;
  f32x4 acc0 = {0.f,0.f,0.f,0.f}, acc1 = {0.f,0.f,0.f,0.f};
  const f16* arow = hsm + (rt*16 + m)*STR + q*8;
  const f16x8* bp0 = (const f16x8*)Wfm + ((size_t)(jb*4+ctb  )*17)*64 + lane;
  const f16x8* bp1 = (const f16x8*)Wfm + ((size_t)(jb*4+ctb+1)*17)*64 + lane;
  #pragma unroll
  for(int kk=0;kk<17;kk++){
    f16x8 a  = *(const f16x8*)(arow + kk*32);
    f16x8 b0 = bp0[kk*64];
    f16x8 b1 = bp1[kk*64];
    acc0 = __builtin_amdgcn_mfma_f32_16x16x32_f16(a, b0, acc0, 0,0,0);
    acc1 = __builtin_amdgcn_mfma_f32_16x16x32_f16(a, b1, acc1, 0,0,0);
  }
  #pragma unroll
  for(int r=0;r<4;r++){
    gt[(ctb  )*16 + m][rt*16 + q*4 + r] = acc0[r];   // C/D: col=lane&15, row=4q+r
    gt[(ctb+1)*16 + m][rt*16 + q*4 + r] = acc1[r];
  }
  __syncthreads();

  #pragma unroll
  for(int qq=0;qq<2;qq++){
    int idx = tid + qq*256;
    int jc = idx & 15, rr = idx >> 4;
    float gi = gt[jc][rr];
    float gf = gt[16+jc][rr];
    float gg = gt[32+jc][rr];
    float go = gt[48+jc][rr];
    int b = b0 + rr, j = jb*16 + jc;
    size_t ci = (size_t)b*HH + j;
    float cv = sigm(gf)*cbuf[ci] + sigm(gi)*tanh_f(gg);
    cbuf[ci] = cv;
    float hv = sigm(go)*tanh_f(cv);
    hout[ci] = (f16)hv;
    hx[((size_t)b*SS + t)*HH + j] = (f16)hv;
  }
}

// ---------------------------------------------------------------------------
// qproj (MFMA): qt[b][n] = h@Wqk^T + bqk : block 32 b x 64 n, grid (8,8)
// ---------------------------------------------------------------------------
__launch_bounds__(256)
__global__ void qproj(const f16* __restrict__ hin, const f16* __restrict__ Wfm,
                      float* __restrict__ qt){
  __shared__ f16 hsm[32*STR];
  const int tid = threadIdx.x;
  const int b0 = blockIdx.x*32, jb = blockIdx.y;
  {
    int row = tid>>3, c0 = tid&7;
    const uint4* src = (const uint4*)(hin + (size_t)(b0+row)*HH);
    uint4* drow = (uint4*)(hsm + row*STR);
    #pragma unroll
    for(int i=0;i<8;i++) drow[c0 + 8*i] = src[c0 + 8*i];
  }
  if(tid < 128){
    int row = tid>>2, pc = tid&3;
    union { f16 h[8]; uint4 u4; } z;
    #pragma unroll
    for(int j=0;j<8;j++) z.h[j] = (f16)0.0f;
    if(pc==0) z.h[0] = (f16)1.0f;
    *((uint4*)(hsm + row*STR) + 64 + pc) = z.u4;
  }
  __syncthreads();

  const int lane = tid & 63, w = tid>>6;
  const int rt = w & 1, ctb = (w>>1)*2;
  const int m = lane & 15, q = lane>>4;
  f32x4 acc0 = {0.f,0.f,0.f,0.f}, acc1 = {0.f,0.f,0.f,0.f};
  const f16* arow = hsm + (rt*16 + m)*STR + q*8;
  const f16x8* bp0 = (const f16x8*)Wfm + ((size_t)(jb*4+ctb  )*17)*64 + lane;
  const f16x8* bp1 = (const f16x8*)Wfm + ((size_t)(jb*4+ctb+1)*17)*64 + lane;
  #pragma unroll
  for(int kk=0;kk<17;kk++){
    f16x8 a  = *(const f16x8*)(arow + kk*32);
    f16x8 b0 = bp0[kk*64];
    f16x8 b1 = bp1[kk*64];
    acc0 = __builtin_amdgcn_mfma_f32_16x16x32_f16(a, b0, acc0, 0,0,0);
    acc1 = __builtin_amdgcn_mfma_f32_16x16x32_f16(a, b1, acc1, 0,0,0);
  }
  #pragma unroll
  for(int r=0;r<4;r++){
    int b = b0 + rt*16 + q*4 + r;
    qt[(size_t)b*HH + jb*64 + (ctb  )*16 + m] = acc0[r];
    qt[(size_t)b*HH + jb*64 + (ctb+1)*16 + m] = acc1[r];
  }
}

// ---------------------------------------------------------------------------
// Attention (flash-style, unchanged structure; hx/ctx now f16)
// ---------------------------------------------------------------------------
__launch_bounds__(256)
__global__ void attn(const float* __restrict__ qt, const f16* __restrict__ hx,
                     f16* __restrict__ ctx){
  __shared__ unsigned short xs[32][520];
  __shared__ float sc[32];
  const int b = blockIdx.x, tid = threadIdx.x;
  const int seg = tid & 7;
  const int sp  = tid >> 3;

  float qreg[64];
  {
    const float4* qv = (const float4*)(qt + (size_t)b*HH + seg*64);
    #pragma unroll
    for(int i=0;i<16;i++){
      float4 v4 = qv[i];
      qreg[i*4+0]=v4.x; qreg[i*4+1]=v4.y; qreg[i*4+2]=v4.z; qreg[i*4+3]=v4.w;
    }
  }

  float m = -1e30f, l = 0.f, a0 = 0.f, a1 = 0.f;
  const uint4* src = (const uint4*)(hx + (size_t)b*SS*HH);

  for(int tile=0; tile<16; ++tile){
    __syncthreads();
    const uint4* tsrc = src + (size_t)tile*2048;
    #pragma unroll
    for(int kk=0;kk<8;kk++){
      uint4 vv = tsrc[kk*256 + tid];
      int e  = (kk*256 + tid)*8;
      int ss = e >> 9, hh = e & 511;
      *(uint4*)&xs[ss][hh] = vv;
    }
    __syncthreads();

    float p = 0.f;
    const uint4* xrow = (const uint4*)&xs[sp][seg*64];
    #pragma unroll
    for(int i=0;i<8;i++){
      uint4 vv = xrow[i];
      float2 t0 = cvt2(vv.x), t1 = cvt2(vv.y), t2 = cvt2(vv.z), t3 = cvt2(vv.w);
      p = fmaf(qreg[i*8+0], t0.x, p);
      p = fmaf(qreg[i*8+1], t0.y, p);
      p = fmaf(qreg[i*8+2], t1.x, p);
      p = fmaf(qreg[i*8+3], t1.y, p);
      p = fmaf(qreg[i*8+4], t2.x, p);
      p = fmaf(qreg[i*8+5], t2.y, p);
      p = fmaf(qreg[i*8+6], t3.x, p);
      p = fmaf(qreg[i*8+7], t3.y, p);
    }
    p += __shfl_xor(p, 1);
    p += __shfl_xor(p, 2);
    p += __shfl_xor(p, 4);
    if(seg == 0) sc[sp] = p;
    __syncthreads();

    float tmax = -1e30f;
    #pragma unroll
    for(int s2=0;s2<32;s2++) tmax = fmaxf(tmax, sc[s2]);
    float mnew  = fmaxf(m, tmax);
    float alpha = __expf(m - mnew);
    a0 *= alpha; a1 *= alpha; l *= alpha;
    #pragma unroll 4
    for(int s2=0;s2<32;s2++){
      float pv = __expf(sc[s2] - mnew);
      l += pv;
      u32 xv = *(const u32*)&xs[s2][2*tid];
      float2 xf = cvt2(xv);
      a0 = fmaf(pv, xf.x, a0);
      a1 = fmaf(pv, xf.y, a1);
    }
    m = mnew;
  }
  float inv = 1.0f/l;
  union { u32 u; f16 h[2]; } pk;
  pk.h[0] = (f16)(a0*inv); pk.h[1] = (f16)(a1*inv);
  *(u32*)(ctx + (size_t)b*HH + 2*tid) = pk.u;
}

// ---------------------------------------------------------------------------
// Decoder step (MFMA): block = 16 batch x 128 gate-cols, grid (16,16), K=1056
// h_ext = [h(512) | ctx(512) | 1 | 0...], W_ext = [Wih+Whh | Wih_ctx | bd | 0...]
// ---------------------------------------------------------------------------
#define STRD 1064  // 1056 data + 8 pad (2128B)

__launch_bounds__(256)
__global__ void dec_step(const f16* __restrict__ hin, f16* __restrict__ hout,
                         float* __restrict__ cbuf, const f16* __restrict__ ctxv,
                         const f16* __restrict__ Wfm, f16* __restrict__ hdec, int t){
  __shared__ f16 hsm[16*STRD];
  __shared__ float gt[128][17];
  const int tid = threadIdx.x;
  const int b0 = blockIdx.x*16, jb = blockIdx.y;

  {
    int row = tid>>4, c0 = tid&15;
    const uint4* srch = (const uint4*)(hin  + (size_t)(b0+row)*HH);
    const uint4* srcc = (const uint4*)(ctxv + (size_t)(b0+row)*HH);
    uint4* drow = (uint4*)(hsm + row*STRD);
    #pragma unroll
    for(int i=0;i<8;i++){
      int c = c0 + 16*i;
      drow[c] = (c < 64) ? srch[c] : srcc[c-64];
    }
  }
  if(tid < 64){
    int row = tid>>2, pc = tid&3;
    union { f16 h[8]; uint4 u4; } z;
    #pragma unroll
    for(int j=0;j<8;j++) z.h[j] = (f16)0.0f;
    if(pc==0) z.h[0] = (f16)1.0f;
    *((uint4*)(hsm + row*STRD) + 128 + pc) = z.u4;
  }
  __syncthreads();

  const int lane = tid & 63, w = tid>>6;
  const int ctb = w*2;
  const int m = lane & 15, q = lane>>4;
  f32x4 acc0 = {0.f,0.f,0.f,0.f}, acc1 = {0.f,0.f,0.f,0.f};
  const f16* arow = hsm + m*STRD + q*8;
  const f16x8* bp0 = (const f16x8*)Wfm + ((size_t)(jb*8+ctb  )*33)*64 + lane;
  const f16x8* bp1 = (const f16x8*)Wfm + ((size_t)(jb*8+ctb+1)*33)*64 + lane;
  #pragma unroll
  for(int kk=0;kk<33;kk++){
    f16x8 a  = *(const f16x8*)(arow + kk*32);
    f16x8 b0 = bp0[kk*64];
    f16x8 b1 = bp1[kk*64];
    acc0 = __builtin_amdgcn_mfma_f32_16x16x32_f16(a, b0, acc0, 0,0,0);
    acc1 = __builtin_amdgcn_mfma_f32_16x16x32_f16(a, b1, acc1, 0,0,0);
  }
  #pragma unroll
  for(int r=0;r<4;r++){
    gt[(ctb  )*16 + m][q*4 + r] = acc0[r];
    gt[(ctb+1)*16 + m][q*4 + r] = acc1[r];
  }
  __syncthreads();

  #pragma unroll
  for(int qq=0;qq<2;qq++){
    int idx = tid + qq*256;
    int jc = idx & 31, rr = idx >> 5;    // jc 0..31, rr 0..15
    float gi = gt[jc][rr];
    float gf = gt[32+jc][rr];
    float gg = gt[64+jc][rr];
    float go = gt[96+jc][rr];
    int b = b0 + rr, j = jb*32 + jc;
    size_t ci = (size_t)b*HH + j;
    float cv = sigm(gf)*cbuf[ci] + sigm(gi)*tanh_f(gg);
    cbuf[ci] = cv;
    float hv = sigm(go)*tanh_f(cv);
    hout[ci] = (f16)hv;
    hdec[((size_t)t*BB + b)*HH + j] = (f16)hv;
  }
}

// out[b,t] = hdec[t,b,:] . out_W + out_b
__launch_bounds__(256)
__global__ void final_out(const f16* __restrict__ hdec, const float* __restrict__ outW,
                          const float* __restrict__ outb, float* __restrict__ out){
  __shared__ float w[HH];
  int t = blockIdx.x;
  for(int i=threadIdx.x;i<HH;i+=256) w[i] = outW[i];
  __syncthreads();
  int b = threadIdx.x;
  const uint4* hp = (const uint4*)(hdec + ((size_t)t*BB + b)*HH);
  float s = 0.f;
  #pragma unroll 4
  for(int j=0;j<HH/8;j++){
    uint4 hv = hp[j];
    float2 t0 = cvt2(hv.x), t1 = cvt2(hv.y), t2 = cvt2(hv.z), t3 = cvt2(hv.w);
    s = fmaf(t0.x, w[j*8+0], s); s = fmaf(t0.y, w[j*8+1], s);
    s = fmaf(t1.x, w[j*8+2], s); s = fmaf(t1.y, w[j*8+3], s);
    s = fmaf(t2.x, w[j*8+4], s); s = fmaf(t2.y, w[j*8+5], s);
    s = fmaf(t3.x, w[j*8+6], s); s = fmaf(t3.y, w[j*8+7], s);
  }
  out[(size_t)b*TT + t] = s + outb[0];
}

// ---------------------------------------------------------------------------
extern "C" void kernel_launch(void* const* d_in, const int* in_sizes, int n_in,
                              void* d_out, int out_size, void* d_ws, size_t ws_size,
                              hipStream_t stream){
  const float* enc_in = (const float*)d_in[0];
  const float* embW = (const float*)d_in[2];
  const float* embB = (const float*)d_in[3];
  const float* eWih = (const float*)d_in[4];
  const float* eWhh = (const float*)d_in[5];
  const float* ebih = (const float*)d_in[6];
  const float* ebhh = (const float*)d_in[7];
  const float* dWih = (const float*)d_in[8];
  const float* dWhh = (const float*)d_in[9];
  const float* dbih = (const float*)d_in[10];
  const float* dbhh = (const float*)d_in[11];
  const float* Wq   = (const float*)d_in[12];
  const float* bq   = (const float*)d_in[13];
  const float* Wk   = (const float*)d_in[14];
  // d_in[15]: bk — softmax-invariant, unused
  const float* outW = (const float*)d_in[16];
  const float* outb = (const float*)d_in[17];

  // ---- workspace layout (byte offsets, all 16B-aligned) ----
  char* base = (char*)d_ws;
  f16* Wenc = (f16*)(base + 0);              // 128*17*64*8 f16 = 2,228,224 B
  f16* Wdec = (f16*)(base + 2228224);        // 128*33*64*8 f16 = 4,325,376 B
  f16* Wqf  = (f16*)(base + 6553600);        // 32*17*64*8 f16 = 557,056 B
  f16* hb0  = (f16*)(base + 7110656);        // 262,144 B
  f16* hb1  = (f16*)(base + 7372800);        // 262,144 B
  f16* ctx  = (f16*)(base + 7634944);        // 262,144 B
  f16* hdec = (f16*)(base + 7897088);        // 25,165,824 B
  f16* hx   = (f16*)(base + 33062912);       // 134,217,728 B
  float* u     = (float*)(base + 167280640); // 8,192 B
  float* v     = (float*)(base + 167288832);
  float* bd    = (float*)(base + 167297024);
  float* bqk   = (float*)(base + 167305216); // 2,048 B
  float* Wqk_t = (float*)(base + 167307264); // 1,048,576 B
  float* cb    = (float*)(base + 168355840); // 524,288 B
  float* qt    = (float*)(base + 168880128); // 524,288 B

  hipMemsetAsync(hb0, 0, (size_t)BB*HH*sizeof(f16), stream);
  hipMemsetAsync(cb,  0, (size_t)BB*HH*sizeof(float), stream);

  prep_uv  <<<8, 256, 0, stream>>>(eWih, embW, embB, ebih, ebhh, dbih, dbhh, u, v, bd);
  prep_bqk <<<2, 256, 0, stream>>>(bq, Wk, bqk);
  prep_wqk <<<512, 256, 0, stream>>>(Wq, Wk, Wqk_t);
  prep_wenc<<<dim3(128,17), 64, 0, stream>>>(eWhh, u, v, Wenc);
  prep_wdec<<<dim3(128,33), 64, 0, stream>>>(dWih, dWhh, bd, Wdec);
  prep_wqfm<<<dim3(32,17),  64, 0, stream>>>(Wqk_t, bqk, Wqf);

  f16* hbuf[2] = {hb0, hb1};
  for(int t=0;t<SS;t++){
    enc_step<<<dim3(8,32), 256, 0, stream>>>(hbuf[t&1], hbuf[(t+1)&1], cb,
                                             Wenc, enc_in, hx, t);
  }
  for(int t=0;t<TT;t++){
    qproj   <<<dim3(8,8),  256, 0, stream>>>(hbuf[t&1], Wqf, qt);
    attn    <<<256, 256, 0, stream>>>(qt, hx, ctx);
    dec_step<<<dim3(16,16),256, 0, stream>>>(hbuf[t&1], hbuf[(t+1)&1], cb, ctx,
                                             Wdec, hdec, t);
  }
  final_out<<<TT, 256, 0, stream>>>(hdec, outW, outb, (float*)d_out);
}